// Round 1
// baseline (14270.464 us; speedup 1.0000x reference)
//
#include <hip/hip_runtime.h>
#include <float.h>
#include <math.h>
#include <stdint.h>

#define LT 1360
#define BB 4
#define DM 512
#define NHH 8

// ---------------- block helpers (sizes 1024,256,64,16; starts 0,1024,1280,1344)
__device__ __forceinline__ void blk_info(int i, int& bi, int& st, int& n){
    if (i < 1024){ bi = 0; st = 0;    n = 1024; }
    else if (i < 1280){ bi = 1; st = 1024; n = 256; }
    else if (i < 1344){ bi = 2; st = 1280; n = 64; }
    else { bi = 3; st = 1344; n = 16; }
}

// ---------------- temporal mask: 1 = banned
__global__ __launch_bounds__(256)
void build_tmask(uint8_t* __restrict__ tm){
    int idx = blockIdx.x * 256 + threadIdx.x;
    if (idx >= LT * LT) return;
    int i = idx / LT, j = idx % LT;
    int bi, sti, ni, bj, stj, nj;
    blk_info(i, bi, sti, ni);
    blk_info(j, bj, stj, nj);
    bool allowed = false;
    if (bi == bj){
        int d = i - j; if (d < 0) d = -d;
        if (d <= 2) allowed = true;            // INNER_SIZE//2 = 2
    }
    if (bi == bj + 1){                          // i coarse, j fine (parent-child)
        int p = i - sti;
        int ls = stj + p * 4;
        int rs = (p == ni - 1) ? sti : stj + (p + 1) * 4;
        if (j >= ls && j < rs) allowed = true;
    }
    if (bj == bi + 1){
        int p = j - stj;
        int ls = sti + p * 4;
        int rs = (p == nj - 1) ? stj : sti + (p + 1) * 4;
        if (i >= ls && i < rs) allowed = true;
    }
    tm[idx] = allowed ? 0 : 1;
}

// ---------------- conv weight repack: wr[(k*512+ii)*512 + o] = cw[o][ii][k]
__global__ __launch_bounds__(256)
void repack_w(const float* __restrict__ cw, float* __restrict__ wr){
    int idx = blockIdx.x * 256 + threadIdx.x;   // 2048*512
    int p = idx >> 9;          // k*512+ii
    int o = idx & 511;
    int k = p >> 9;
    int ii = p & 511;
    wr[idx] = cw[((size_t)o * 512 + ii) * 4 + k];
}

// ---------------- generic fp32 GEMM, 64x64 tile, BK=16, 256 thr, 4x4/thread
// C[orow,n] where orow = (row/mpb)*orpb + ooff + row%mpb
// act: 0 none, 1 (x+b)*cscale then ELU, 2 relu
__global__ __launch_bounds__(256)
void gemm_f32(const float* __restrict__ A, const float* __restrict__ Bm,
              const float* __restrict__ bias, const float* __restrict__ Rres,
              float* __restrict__ C, int M, int N, int K,
              int mpb, int orpb, int ooff, int act)
{
    __shared__ float As[16][64];
    __shared__ float Bs[16][64];
    int tid = threadIdx.x;
    int tx = tid & 15, ty = tid >> 4;
    int gm = blockIdx.y << 6, gn = blockIdx.x << 6;
    int lm = tid >> 2, lk4 = (tid & 3) << 2;
    int bk = tid >> 4, bn4 = (tid & 15) << 2;
    float acc[4][4] = {{0.f,0.f,0.f,0.f},{0.f,0.f,0.f,0.f},{0.f,0.f,0.f,0.f},{0.f,0.f,0.f,0.f}};
    for (int k0 = 0; k0 < K; k0 += 16){
        float4 av = *(const float4*)(A + (size_t)(gm + lm) * K + k0 + lk4);
        As[lk4+0][lm] = av.x; As[lk4+1][lm] = av.y;
        As[lk4+2][lm] = av.z; As[lk4+3][lm] = av.w;
        float4 bv = *(const float4*)(Bm + (size_t)(k0 + bk) * N + gn + bn4);
        *(float4*)&Bs[bk][bn4] = bv;
        __syncthreads();
        #pragma unroll
        for (int kk = 0; kk < 16; kk++){
            float ar[4], br[4];
            #pragma unroll
            for (int i = 0; i < 4; i++) ar[i] = As[kk][(ty<<2)+i];
            #pragma unroll
            for (int j = 0; j < 4; j++) br[j] = Bs[kk][(tx<<2)+j];
            #pragma unroll
            for (int i = 0; i < 4; i++)
                #pragma unroll
                for (int j = 0; j < 4; j++)
                    acc[i][j] = fmaf(ar[i], br[j], acc[i][j]);
        }
        __syncthreads();
    }
    const float cscale = 0.9999950000375f;   // 1/sqrt(1+1e-5)
    #pragma unroll
    for (int i = 0; i < 4; i++){
        int row = gm + (ty<<2) + i;
        int orow = (row / mpb) * orpb + ooff + (row % mpb);
        #pragma unroll
        for (int j = 0; j < 4; j++){
            int col = gn + (tx<<2) + j;
            float v = acc[i][j];
            if (bias) v += bias[col];
            if (Rres) v += Rres[(size_t)orow * N + col];
            if (act == 1){ v *= cscale; v = (v > 0.f) ? v : expm1f(v); }
            else if (act == 2){ v = fmaxf(v, 0.f); }
            C[(size_t)orow * N + col] = v;
        }
    }
}

// ---------------- concat conv pyramids: PC (B,336,512) <- C1(B,256,512),C2(B,64,512),C3(B,16,512)
__global__ __launch_bounds__(256)
void pcat_copy(const float* __restrict__ C1, const float* __restrict__ C2,
               const float* __restrict__ C3, float* __restrict__ PC){
    int idx = blockIdx.x * 256 + threadIdx.x;   // 4*336*512
    int d = idx & 511;
    int r = (idx >> 9) % 336;
    int b = idx / (336 * 512);
    float v;
    if (r < 256)       v = C1[(((size_t)b * 256 + r) << 9) + d];
    else if (r < 320)  v = C2[(((size_t)b * 64 + (r - 256)) << 9) + d];
    else               v = C3[(((size_t)b * 16 + (r - 320)) << 9) + d];
    PC[idx] = v;
}

// ---------------- copy x_enc (B,1024,512) into rows [0,1024) of (B,1360,512)
__global__ __launch_bounds__(256)
void xenc_copy(const float* __restrict__ xe, float* __restrict__ dst){
    int idx = blockIdx.x * 256 + threadIdx.x;   // 4*1024*512
    int d = idx & 511;
    int l = (idx >> 9) & 1023;
    int b = idx >> 19;
    dst[(((size_t)b * LT + l) << 9) + d] = xe[idx];
}

// ---------------- LayerNorm over 512, wave per row
__global__ __launch_bounds__(256)
void ln_kernel(const float* __restrict__ in, const float* __restrict__ g,
               const float* __restrict__ bta, float* __restrict__ out, float eps){
    int wid = threadIdx.x >> 6, lane = threadIdx.x & 63;
    int row = blockIdx.x * 4 + wid;
    const float* p = in + ((size_t)row << 9);
    float vals[8]; float s = 0.f, s2 = 0.f;
    #pragma unroll
    for (int t = 0; t < 8; t++){
        float v = p[lane + t * 64]; vals[t] = v; s += v; s2 += v * v;
    }
    #pragma unroll
    for (int off = 32; off; off >>= 1){
        s  += __shfl_xor(s,  off, 64);
        s2 += __shfl_xor(s2, off, 64);
    }
    float mu = s * (1.f / 512.f);
    float var = s2 * (1.f / 512.f) - mu * mu;
    float r = rsqrtf(var + eps);
    float* q = out + ((size_t)row << 9);
    #pragma unroll
    for (int t = 0; t < 8; t++){
        int c = lane + t * 64;
        q[c] = (vals[t] - mu) * r * g[c] + bta[c];
    }
}

// ---------------- row L2-normalize, wave per row
__global__ __launch_bounds__(256)
void rownorm_kernel(const float* __restrict__ in, float* __restrict__ out){
    int wid = threadIdx.x >> 6, lane = threadIdx.x & 63;
    int row = blockIdx.x * 4 + wid;
    const float* p = in + ((size_t)row << 9);
    float vals[8]; float s2 = 0.f;
    #pragma unroll
    for (int t = 0; t < 8; t++){
        float v = p[lane + t * 64]; vals[t] = v; s2 += v * v;
    }
    #pragma unroll
    for (int off = 32; off; off >>= 1) s2 += __shfl_xor(s2, off, 64);
    float inv = 1.f / fmaxf(sqrtf(s2), 1e-8f);
    float* q = out + ((size_t)row << 9);
    #pragma unroll
    for (int t = 0; t < 8; t++) q[lane + t * 64] = vals[t] * inv;
}

// ---------------- semantic top-k per row within its diagonal block
__global__ __launch_bounds__(256)
void topk_kernel(const float* __restrict__ XNp, uint8_t* __restrict__ SM){
    __shared__ float sim[1024];
    __shared__ float qrow[512];
    __shared__ float rv[256];
    __shared__ int   ri[256];
    int r = blockIdx.x;               // 0..B*LT-1
    int b = r / LT, i = r % LT;
    int bi, st, n; blk_info(i, bi, st, n);
    int tid = threadIdx.x;
    const float* xr = XNp + (((size_t)b * LT + i) << 9);
    for (int d = tid; d < 512; d += 256) qrow[d] = xr[d];
    __syncthreads();
    for (int j = tid; j < n; j += 256){
        const float4* xc = (const float4*)(XNp + (((size_t)b * LT + st + j) << 9));
        float acc = 0.f;
        #pragma unroll 4
        for (int d = 0; d < 128; d++){
            float4 x4 = xc[d];
            acc += qrow[4*d+0]*x4.x + qrow[4*d+1]*x4.y + qrow[4*d+2]*x4.z + qrow[4*d+3]*x4.w;
        }
        sim[j] = acc;
    }
    __syncthreads();
    int k = (n < 32) ? n : 32;
    uint8_t* mrow = SM + ((size_t)b * LT + i) * LT + st;
    for (int it = 0; it < k; it++){
        float bv = -FLT_MAX; int bidx = 1 << 30;
        for (int j = tid; j < n; j += 256){
            float v = sim[j];
            if (v > bv || (v == bv && j < bidx)){ bv = v; bidx = j; }
        }
        rv[tid] = bv; ri[tid] = bidx;
        __syncthreads();
        for (int s = 128; s; s >>= 1){
            if (tid < s){
                float ov = rv[tid + s]; int oi = ri[tid + s];
                if (ov > rv[tid] || (ov == rv[tid] && oi < ri[tid])){ rv[tid] = ov; ri[tid] = oi; }
            }
            __syncthreads();
        }
        if (tid == 0){ mrow[ri[0]] = 1; sim[ri[0]] = -FLT_MAX; }
        __syncthreads();
    }
}

// ---------------- streaming-softmax attention, wave per (b,h,q) row
__global__ __launch_bounds__(256)
void attn_kernel(const float* __restrict__ Q, const float* __restrict__ Kp,
                 const float* __restrict__ Vp, const uint8_t* __restrict__ Mk,
                 long mbstride, float* __restrict__ O){
    int wid = threadIdx.x >> 6, lane = threadIdx.x & 63;
    int row = blockIdx.x * 4 + wid;            // B*H*LT rows
    int b = row / (NHH * LT);
    int rem = row % (NHH * LT);
    int h = rem / LT, i = rem % LT;
    float qd = Q[(((size_t)b * LT + i) << 9) + h * 64 + lane];
    const float* kb = Kp + (((size_t)b * LT) << 9) + h * 64 + lane;
    const float* vb = Vp + (((size_t)b * LT) << 9) + h * 64 + lane;
    const uint8_t* mrow = Mk + (size_t)b * mbstride + (size_t)i * LT;
    float m = -FLT_MAX, lsum = 0.f, o = 0.f;
    for (int j = 0; j < LT; j++){
        if (mrow[j]) continue;
        float s = qd * kb[(size_t)j << 9];
        #pragma unroll
        for (int off = 32; off; off >>= 1) s += __shfl_xor(s, off, 64);
        s *= 0.125f;                            // 1/sqrt(64)
        float mn = fmaxf(m, s);
        float sc = __expf(m - mn);
        float p  = __expf(s - mn);
        lsum = lsum * sc + p;
        o = o * sc + p * vb[(size_t)j << 9];
        m = mn;
    }
    O[(((size_t)b * LT + i) << 9) + h * 64 + lane] = o / lsum;
}

// ---------------- x = (t + s + x)/3
__global__ __launch_bounds__(256)
void add3_kernel(const float* __restrict__ T, const float* __restrict__ S,
                 float* __restrict__ X){
    size_t idx = (size_t)blockIdx.x * 256 + threadIdx.x;
    X[idx] = (T[idx] + S[idx] + X[idx]) * (1.f / 3.f);
}

extern "C" void kernel_launch(void* const* d_in, const int* in_sizes, int n_in,
                              void* d_out, int out_size, void* d_ws, size_t ws_size,
                              hipStream_t stream)
{
    const float* x_enc   = (const float*)d_in[0];
    const float* down_W  = (const float*)d_in[1];
    const float* down_b  = (const float*)d_in[2];
    const float* conv_W  = (const float*)d_in[3];
    const float* conv_b  = (const float*)d_in[4];
    const float* up_W    = (const float*)d_in[5];
    const float* up_b    = (const float*)d_in[6];
    const float* bc_g    = (const float*)d_in[7];
    const float* bc_b    = (const float*)d_in[8];
    const float* aWq     = (const float*)d_in[9];
    const float* aWk     = (const float*)d_in[10];
    const float* aWv     = (const float*)d_in[11];
    const float* afcW    = (const float*)d_in[12];
    const float* afcb    = (const float*)d_in[13];
    const float* alng    = (const float*)d_in[14];
    const float* alnb    = (const float*)d_in[15];
    const float* fW1     = (const float*)d_in[16];
    const float* fb1     = (const float*)d_in[17];
    const float* fW2     = (const float*)d_in[18];
    const float* fb2     = (const float*)d_in[19];
    const float* flng    = (const float*)d_in[20];
    const float* flnb    = (const float*)d_in[21];

    const size_t NBL = (size_t)BB * LT * 512;   // 2,785,280
    float* W   = (float*)d_ws;
    float* X   = W;
    float* TMP = X   + NBL;
    float* Qb  = TMP + NBL;
    float* Kb  = Qb  + NBL;
    float* Vb  = Kb  + NBL;
    float* AO  = Vb  + NBL;
    float* TO  = AO  + NBL;
    float* SO  = TO  + NBL;
    uint8_t* TM = (uint8_t*)(SO + NBL);
    uint8_t* SM = TM + (size_t)LT * LT;
    size_t need = 8 * NBL * sizeof(float) + (size_t)LT * LT * (1 + BB);
    if (ws_size < need) return;   // insufficient scratch — fail loudly via wrong output

    // aliases (lifetimes disjoint)
    float* Y    = Qb;                 // down output (B,1024,512)
    float* C1   = Kb;                 // (B,256,512)
    float* C2   = C1 + (size_t)BB*256*512;
    float* C3   = C2 + (size_t)BB*64*512;
    float* PCAT = Vb;                 // (B,336,512)
    float* WR0  = TO;                 // 3 x (2048,512) repacked conv weights
    float* WR1  = WR0 + (size_t)2048*512;
    float* WR2  = WR1 + (size_t)2048*512;
    float* XN   = AO;                 // normalized rows for semantic sim
    float* Hf   = Qb;                 // FFN hidden

    auto gemm = [&](const float* A, const float* Bm, const float* bias,
                    const float* res, float* C, int M, int N, int K,
                    int mpb, int orpb, int ooff, int act){
        dim3 grid(N / 64, M / 64);
        gemm_f32<<<grid, 256, 0, stream>>>(A, Bm, bias, res, C, M, N, K, mpb, orpb, ooff, act);
    };

    // masks + weight repack
    build_tmask<<<(LT * LT) / 256, 256, 0, stream>>>(TM);
    repack_w<<<4096, 256, 0, stream>>>(conv_W + 0 * (size_t)512*512*4, WR0);
    repack_w<<<4096, 256, 0, stream>>>(conv_W + 1 * (size_t)512*512*4, WR1);
    repack_w<<<4096, 256, 0, stream>>>(conv_W + 2 * (size_t)512*512*4, WR2);

    // ---- bottleneck
    gemm(x_enc, down_W, down_b, nullptr, Y, BB*1024, 512, 512, BB*1024, 0, 0, 0);
    gemm(Y,  WR0, conv_b + 0,    nullptr, C1, BB*256, 512, 2048, BB*256, 0, 0, 1);
    gemm(C1, WR1, conv_b + 512,  nullptr, C2, BB*64,  512, 2048, BB*64,  0, 0, 1);
    gemm(C2, WR2, conv_b + 1024, nullptr, C3, BB*16,  512, 2048, BB*16,  0, 0, 1);
    pcat_copy<<<(BB*336*512)/256, 256, 0, stream>>>(C1, C2, C3, PCAT);
    gemm(PCAT, up_W, up_b, nullptr, TMP, BB*336, 512, 512, 336, LT, 1024, 0);
    xenc_copy<<<(BB*1024*512)/256, 256, 0, stream>>>(x_enc, TMP);
    ln_kernel<<<(BB*LT)/4, 256, 0, stream>>>(TMP, bc_g, bc_b, X, 1e-5f);

    // ---- transformer layers
    for (int l = 0; l < 2; l++){
        // semantic mask from current X
        hipMemsetAsync(SM, 0, (size_t)BB * LT * LT, stream);
        rownorm_kernel<<<(BB*LT)/4, 256, 0, stream>>>(X, XN);
        topk_kernel<<<BB*LT, 256, 0, stream>>>(XN, SM);

        for (int j = 0; j < 2; j++){
            const float* Wq = aWq  + ((size_t)(l*2 + j)) * 512 * 512;
            const float* Wk = aWk  + ((size_t)(l*2 + j)) * 512 * 512;
            const float* Wv = aWv  + ((size_t)(l*2 + j)) * 512 * 512;
            const float* Wf = afcW + ((size_t)(l*2 + j)) * 512 * 512;
            const float* bf = afcb + (size_t)(l*2 + j) * 512;
            const float* lg = alng + (size_t)(l*2 + j) * 512;
            const float* lb = alnb + (size_t)(l*2 + j) * 512;
            gemm(X, Wq, nullptr, nullptr, Qb, BB*LT, 512, 512, BB*LT, 0, 0, 0);
            gemm(X, Wk, nullptr, nullptr, Kb, BB*LT, 512, 512, BB*LT, 0, 0, 0);
            gemm(X, Wv, nullptr, nullptr, Vb, BB*LT, 512, 512, BB*LT, 0, 0, 0);
            if (j == 0)
                attn_kernel<<<(BB*NHH*LT)/4, 256, 0, stream>>>(Qb, Kb, Vb, TM, 0L, AO);
            else
                attn_kernel<<<(BB*NHH*LT)/4, 256, 0, stream>>>(Qb, Kb, Vb, SM, (long)LT*LT, AO);
            gemm(AO, Wf, bf, X, TMP, BB*LT, 512, 512, BB*LT, 0, 0, 0);
            ln_kernel<<<(BB*LT)/4, 256, 0, stream>>>(TMP, lg, lb, (j == 0) ? TO : SO, 1e-6f);
        }
        add3_kernel<<<(int)(NBL/256), 256, 0, stream>>>(TO, SO, X);

        // FFN
        gemm(X,  fW1 + (size_t)l*512*512, fb1 + (size_t)l*512, nullptr, Hf, BB*LT, 512, 512, BB*LT, 0, 0, 2);
        gemm(Hf, fW2 + (size_t)l*512*512, fb2 + (size_t)l*512, X,       TMP, BB*LT, 512, 512, BB*LT, 0, 0, 0);
        ln_kernel<<<(BB*LT)/4, 256, 0, stream>>>(TMP, flng + (size_t)l*512, flnb + (size_t)l*512,
                                                 (l == 1) ? (float*)d_out : X, 1e-6f);
    }
}

// Round 2
// 4585.829 us; speedup vs baseline: 3.1119x; 3.1119x over previous
//
#include <hip/hip_runtime.h>
#include <float.h>
#include <math.h>
#include <stdint.h>

#define LT 1360
#define BB 4
#define DM 512
#define NHH 8

// ---------------- block helpers (sizes 1024,256,64,16; starts 0,1024,1280,1344)
__device__ __forceinline__ void blk_info(int i, int& bi, int& st, int& n){
    if (i < 1024){ bi = 0; st = 0;    n = 1024; }
    else if (i < 1280){ bi = 1; st = 1024; n = 256; }
    else if (i < 1344){ bi = 2; st = 1280; n = 64; }
    else { bi = 3; st = 1344; n = 16; }
}

// ---------------- temporal allowed-index lists: TIDX[i*12+t], TCNT[i]
__global__ __launch_bounds__(256)
void build_tidx(int* __restrict__ idx, int* __restrict__ cnt){
    int i = blockIdx.x * 256 + threadIdx.x;
    if (i >= LT) return;
    int bi, st, n; blk_info(i, bi, st, n);
    int c = 0; int* row = idx + i * 12;
    int lo = (i - 2 > st) ? i - 2 : st;
    int hi = (i + 2 < st + n - 1) ? i + 2 : st + n - 1;
    for (int j = lo; j <= hi; j++) row[c++] = j;       // inner window (incl self)
    if (bi < 3) row[c++] = st + n + (i - st) / 4;      // parent in next (coarser) block
    if (bi > 0){                                        // 4 children in previous block
        int stc = st - n * 4;
        int base = stc + (i - st) * 4;
        for (int t = 0; t < 4; t++) row[c++] = base + t;
    }
    cnt[i] = c;
}

// ---------------- conv weight repack: wr[(k*512+ii)*512 + o] = cw[o][ii][k]
__global__ __launch_bounds__(256)
void repack_w(const float* __restrict__ cw, float* __restrict__ wr){
    int idx = blockIdx.x * 256 + threadIdx.x;   // 2048*512
    int p = idx >> 9;          // k*512+ii
    int o = idx & 511;
    int k = p >> 9;
    int ii = p & 511;
    wr[idx] = cw[((size_t)o * 512 + ii) * 4 + k];
}

// ---------------- generic fp32 GEMM, 64x64 tile, BK=16, 256 thr, 4x4/thread
__global__ __launch_bounds__(256)
void gemm_f32(const float* __restrict__ A, const float* __restrict__ Bm,
              const float* __restrict__ bias, const float* __restrict__ Rres,
              float* __restrict__ C, int M, int N, int K,
              int mpb, int orpb, int ooff, int act)
{
    __shared__ float As[16][64];
    __shared__ float Bs[16][64];
    int tid = threadIdx.x;
    int tx = tid & 15, ty = tid >> 4;
    int gm = blockIdx.y << 6, gn = blockIdx.x << 6;
    int lm = tid >> 2, lk4 = (tid & 3) << 2;
    int bk = tid >> 4, bn4 = (tid & 15) << 2;
    float acc[4][4] = {{0.f,0.f,0.f,0.f},{0.f,0.f,0.f,0.f},{0.f,0.f,0.f,0.f},{0.f,0.f,0.f,0.f}};
    for (int k0 = 0; k0 < K; k0 += 16){
        float4 av = *(const float4*)(A + (size_t)(gm + lm) * K + k0 + lk4);
        As[lk4+0][lm] = av.x; As[lk4+1][lm] = av.y;
        As[lk4+2][lm] = av.z; As[lk4+3][lm] = av.w;
        float4 bv = *(const float4*)(Bm + (size_t)(k0 + bk) * N + gn + bn4);
        *(float4*)&Bs[bk][bn4] = bv;
        __syncthreads();
        #pragma unroll
        for (int kk = 0; kk < 16; kk++){
            float ar[4], br[4];
            #pragma unroll
            for (int i = 0; i < 4; i++) ar[i] = As[kk][(ty<<2)+i];
            #pragma unroll
            for (int j = 0; j < 4; j++) br[j] = Bs[kk][(tx<<2)+j];
            #pragma unroll
            for (int i = 0; i < 4; i++)
                #pragma unroll
                for (int j = 0; j < 4; j++)
                    acc[i][j] = fmaf(ar[i], br[j], acc[i][j]);
        }
        __syncthreads();
    }
    const float cscale = 0.9999950000375f;   // 1/sqrt(1+1e-5)
    #pragma unroll
    for (int i = 0; i < 4; i++){
        int row = gm + (ty<<2) + i;
        int orow = (row / mpb) * orpb + ooff + (row % mpb);
        #pragma unroll
        for (int j = 0; j < 4; j++){
            int col = gn + (tx<<2) + j;
            float v = acc[i][j];
            if (bias) v += bias[col];
            if (Rres) v += Rres[(size_t)orow * N + col];
            if (act == 1){ v *= cscale; v = (v > 0.f) ? v : expm1f(v); }
            else if (act == 2){ v = fmaxf(v, 0.f); }
            C[(size_t)orow * N + col] = v;
        }
    }
}

// ---------------- concat conv pyramids
__global__ __launch_bounds__(256)
void pcat_copy(const float* __restrict__ C1, const float* __restrict__ C2,
               const float* __restrict__ C3, float* __restrict__ PC){
    int idx = blockIdx.x * 256 + threadIdx.x;   // 4*336*512
    int d = idx & 511;
    int r = (idx >> 9) % 336;
    int b = idx / (336 * 512);
    float v;
    if (r < 256)       v = C1[(((size_t)b * 256 + r) << 9) + d];
    else if (r < 320)  v = C2[(((size_t)b * 64 + (r - 256)) << 9) + d];
    else               v = C3[(((size_t)b * 16 + (r - 320)) << 9) + d];
    PC[idx] = v;
}

// ---------------- copy x_enc (B,1024,512) into rows [0,1024) of (B,1360,512)
__global__ __launch_bounds__(256)
void xenc_copy(const float* __restrict__ xe, float* __restrict__ dst){
    int idx = blockIdx.x * 256 + threadIdx.x;   // 4*1024*512
    int d = idx & 511;
    int l = (idx >> 9) & 1023;
    int b = idx >> 19;
    dst[(((size_t)b * LT + l) << 9) + d] = xe[idx];
}

// ---------------- LayerNorm over 512, wave per row
__global__ __launch_bounds__(256)
void ln_kernel(const float* __restrict__ in, const float* __restrict__ g,
               const float* __restrict__ bta, float* __restrict__ out, float eps){
    int wid = threadIdx.x >> 6, lane = threadIdx.x & 63;
    int row = blockIdx.x * 4 + wid;
    const float* p = in + ((size_t)row << 9);
    float vals[8]; float s = 0.f, s2 = 0.f;
    #pragma unroll
    for (int t = 0; t < 8; t++){
        float v = p[lane + t * 64]; vals[t] = v; s += v; s2 += v * v;
    }
    #pragma unroll
    for (int off = 32; off; off >>= 1){
        s  += __shfl_xor(s,  off, 64);
        s2 += __shfl_xor(s2, off, 64);
    }
    float mu = s * (1.f / 512.f);
    float var = s2 * (1.f / 512.f) - mu * mu;
    float r = rsqrtf(var + eps);
    float* q = out + ((size_t)row << 9);
    #pragma unroll
    for (int t = 0; t < 8; t++){
        int c = lane + t * 64;
        q[c] = (vals[t] - mu) * r * g[c] + bta[c];
    }
}

// ---------------- row L2-normalize, wave per row
__global__ __launch_bounds__(256)
void rownorm_kernel(const float* __restrict__ in, float* __restrict__ out){
    int wid = threadIdx.x >> 6, lane = threadIdx.x & 63;
    int row = blockIdx.x * 4 + wid;
    const float* p = in + ((size_t)row << 9);
    float vals[8]; float s2 = 0.f;
    #pragma unroll
    for (int t = 0; t < 8; t++){
        float v = p[lane + t * 64]; vals[t] = v; s2 += v * v;
    }
    #pragma unroll
    for (int off = 32; off; off >>= 1) s2 += __shfl_xor(s2, off, 64);
    float inv = 1.f / fmaxf(sqrtf(s2), 1e-8f);
    float* q = out + ((size_t)row << 9);
    #pragma unroll
    for (int t = 0; t < 8; t++) q[lane + t * 64] = vals[t] * inv;
}

// ---------------- semantic top-k per row within its diagonal block (banned set)
__global__ __launch_bounds__(256)
void topk_kernel(const float* __restrict__ XNp, uint8_t* __restrict__ SM){
    __shared__ float sim[1024];
    __shared__ float qrow[512];
    __shared__ float rv[256];
    __shared__ int   ri[256];
    int r = blockIdx.x;               // 0..B*LT-1
    int b = r / LT, i = r % LT;
    int bi, st, n; blk_info(i, bi, st, n);
    int tid = threadIdx.x;
    const float* xr = XNp + (((size_t)b * LT + i) << 9);
    for (int d = tid; d < 512; d += 256) qrow[d] = xr[d];
    __syncthreads();
    for (int j = tid; j < n; j += 256){
        const float4* xc = (const float4*)(XNp + (((size_t)b * LT + st + j) << 9));
        float acc = 0.f;
        #pragma unroll 4
        for (int d = 0; d < 128; d++){
            float4 x4 = xc[d];
            acc += qrow[4*d+0]*x4.x + qrow[4*d+1]*x4.y + qrow[4*d+2]*x4.z + qrow[4*d+3]*x4.w;
        }
        sim[j] = acc;
    }
    __syncthreads();
    int k = (n < 32) ? n : 32;
    uint8_t* mrow = SM + ((size_t)b * LT + i) * LT + st;
    for (int it = 0; it < k; it++){
        float bv = -FLT_MAX; int bidx = 1 << 30;
        for (int j = tid; j < n; j += 256){
            float v = sim[j];
            if (v > bv || (v == bv && j < bidx)){ bv = v; bidx = j; }
        }
        rv[tid] = bv; ri[tid] = bidx;
        __syncthreads();
        for (int s = 128; s; s >>= 1){
            if (tid < s){
                float ov = rv[tid + s]; int oi = ri[tid + s];
                if (ov > rv[tid] || (ov == rv[tid] && oi < ri[tid])){ rv[tid] = ov; ri[tid] = oi; }
            }
            __syncthreads();
        }
        if (tid == 0){ mrow[ri[0]] = 1; sim[ri[0]] = -FLT_MAX; }
        __syncthreads();
    }
}

// ---------------- sparse attention via index lists (temporal), wave per (b,h,q)
__global__ __launch_bounds__(256)
void attn_sparse(const float* __restrict__ Q, const float* __restrict__ Kp,
                 const float* __restrict__ Vp, const int* __restrict__ IDX,
                 const int* __restrict__ CNT, float* __restrict__ O){
    int wid = threadIdx.x >> 6, lane = threadIdx.x & 63;
    int row = blockIdx.x * 4 + wid;            // B*H*LT rows
    int b = row / (NHH * LT);
    int rem = row % (NHH * LT);
    int h = rem / LT, i = rem % LT;
    int c = CNT[i];
    int jl = IDX[i * 12 + (lane % 12)];
    float qd = Q[(((size_t)b * LT + i) << 9) + h * 64 + lane];
    const float* kb = Kp + (((size_t)b * LT) << 9) + h * 64 + lane;
    const float* vb = Vp + (((size_t)b * LT) << 9) + h * 64 + lane;
    float m = -FLT_MAX, lsum = 0.f, o = 0.f;
    for (int t = 0; t < c; t++){
        int j = __shfl(jl, t, 64);
        float s = qd * kb[(size_t)j << 9];
        #pragma unroll
        for (int off = 32; off; off >>= 1) s += __shfl_xor(s, off, 64);
        s *= 0.125f;                            // 1/sqrt(64)
        float mn = fmaxf(m, s);
        float sc = __expf(m - mn);
        float p  = __expf(s - mn);
        lsum = lsum * sc + p;
        o = o * sc + p * vb[(size_t)j << 9];
        m = mn;
    }
    O[(((size_t)b * LT + i) << 9) + h * 64 + lane] = o / lsum;
}

// ---------------- dense flash attention with byte mask (semantic)
// grid: x = 22 q-tiles of 64, y = b*8+h. block 256 = 16x16.
__global__ __launch_bounds__(256)
void flash_attn(const float* __restrict__ Q, const float* __restrict__ Kp,
                const float* __restrict__ Vp, const uint8_t* __restrict__ Mk,
                long mbstride, float* __restrict__ O)
{
    __shared__ float Qs[64][65];   // [d][row]
    __shared__ float KP[64][65];   // K tile [d][key], then P tile [key][row]
    __shared__ float Vs[64][68];   // [key][d], pad 68 keeps float4 alignment
    int bh = blockIdx.y, b = bh >> 3, h = bh & 7;
    int q0 = blockIdx.x << 6;
    int tid = threadIdx.x, tx = tid & 15, ty = tid >> 4;

    const float* Qbase = Q + (((size_t)b * LT + q0) << 9) + h * 64;
    #pragma unroll
    for (int c = 0; c < 4; c++){
        int idx = tid + 256 * c;              // 0..1023
        int r = idx >> 4, d4 = (idx & 15) << 2;
        int rr = (q0 + r < LT) ? r : (LT - 1 - q0);
        float4 v = *(const float4*)(Qbase + ((size_t)rr << 9) + d4);
        Qs[d4+0][r] = v.x; Qs[d4+1][r] = v.y; Qs[d4+2][r] = v.z; Qs[d4+3][r] = v.w;
    }
    float acc[4][4] = {{0.f,0.f,0.f,0.f},{0.f,0.f,0.f,0.f},{0.f,0.f,0.f,0.f},{0.f,0.f,0.f,0.f}};
    float m_i[4] = {-FLT_MAX,-FLT_MAX,-FLT_MAX,-FLT_MAX};
    float l_i[4] = {0.f,0.f,0.f,0.f};
    const float* Kbase = Kp + (((size_t)b * LT) << 9) + h * 64;
    const float* Vbase = Vp + (((size_t)b * LT) << 9) + h * 64;
    const uint8_t* Mbase = Mk + (size_t)b * mbstride;

    for (int kt = 0; kt < 22; kt++){
        int k0 = kt << 6;
        __syncthreads();                       // prior PV done; Qs ready on kt=0
        #pragma unroll
        for (int c = 0; c < 4; c++){
            int idx = tid + 256 * c;
            int kk = idx >> 4, d4 = (idx & 15) << 2;
            int gk = k0 + kk; int gkc = (gk < LT) ? gk : (LT - 1);
            float4 kv = *(const float4*)(Kbase + ((size_t)gkc << 9) + d4);
            KP[d4+0][kk] = kv.x; KP[d4+1][kk] = kv.y; KP[d4+2][kk] = kv.z; KP[d4+3][kk] = kv.w;
            float4 vv = *(const float4*)(Vbase + ((size_t)gkc << 9) + d4);
            *(float4*)&Vs[kk][d4] = vv;
        }
        __syncthreads();
        // S = Q K^T (4x4 per thread)
        float s[4][4] = {{0.f,0.f,0.f,0.f},{0.f,0.f,0.f,0.f},{0.f,0.f,0.f,0.f},{0.f,0.f,0.f,0.f}};
        #pragma unroll 8
        for (int d = 0; d < 64; d++){
            float ar[4], br[4];
            #pragma unroll
            for (int i = 0; i < 4; i++) ar[i] = Qs[d][(ty<<2)+i];
            #pragma unroll
            for (int j = 0; j < 4; j++) br[j] = KP[d][(tx<<2)+j];
            #pragma unroll
            for (int i = 0; i < 4; i++)
                #pragma unroll
                for (int j = 0; j < 4; j++)
                    s[i][j] = fmaf(ar[i], br[j], s[i][j]);
        }
        // mask + scale + online softmax
        int kcol = k0 + (tx << 2);
        #pragma unroll
        for (int i = 0; i < 4; i++){
            int qr = q0 + (ty << 2) + i;
            int qrc = (qr < LT) ? qr : (LT - 1);
            uint32_t mw;
            if (kcol + 3 < LT) mw = *(const uint32_t*)(Mbase + (size_t)qrc * LT + kcol);
            else mw = 0xFFFFFFFFu;
            #pragma unroll
            for (int j = 0; j < 4; j++){
                float sv = s[i][j] * 0.125f;
                s[i][j] = ((mw >> (8*j)) & 0xFF) ? -FLT_MAX : sv;
            }
            float tmax = fmaxf(fmaxf(s[i][0], s[i][1]), fmaxf(s[i][2], s[i][3]));
            #pragma unroll
            for (int off = 1; off < 16; off <<= 1) tmax = fmaxf(tmax, __shfl_xor(tmax, off, 64));
            float mn = fmaxf(m_i[i], tmax);
            float alpha = __expf(m_i[i] - mn);
            float psum = 0.f;
            #pragma unroll
            for (int j = 0; j < 4; j++){
                float pv = (s[i][j] <= -1e30f) ? 0.f : __expf(s[i][j] - mn);
                s[i][j] = pv; psum += pv;
            }
            #pragma unroll
            for (int off = 1; off < 16; off <<= 1) psum += __shfl_xor(psum, off, 64);
            l_i[i] = l_i[i] * alpha + psum;
            m_i[i] = mn;
            #pragma unroll
            for (int j = 0; j < 4; j++) acc[i][j] *= alpha;
        }
        __syncthreads();                       // done reading K from KP
        #pragma unroll
        for (int i = 0; i < 4; i++)
            #pragma unroll
            for (int j = 0; j < 4; j++)
                KP[(tx<<2)+j][(ty<<2)+i] = s[i][j];   // P tile [key][row]
        __syncthreads();
        // O += P @ V
        #pragma unroll 8
        for (int kk = 0; kk < 64; kk++){
            float ar[4], br[4];
            #pragma unroll
            for (int i = 0; i < 4; i++) ar[i] = KP[kk][(ty<<2)+i];
            #pragma unroll
            for (int j = 0; j < 4; j++) br[j] = Vs[kk][(tx<<2)+j];
            #pragma unroll
            for (int i = 0; i < 4; i++)
                #pragma unroll
                for (int j = 0; j < 4; j++)
                    acc[i][j] = fmaf(ar[i], br[j], acc[i][j]);
        }
    }
    #pragma unroll
    for (int i = 0; i < 4; i++){
        int qr = q0 + (ty << 2) + i;
        if (qr < LT){
            float inv = 1.f / l_i[i];
            #pragma unroll
            for (int j = 0; j < 4; j++)
                O[(((size_t)b * LT + qr) << 9) + h * 64 + (tx << 2) + j] = acc[i][j] * inv;
        }
    }
}

// ---------------- x = (t + s + x)/3
__global__ __launch_bounds__(256)
void add3_kernel(const float* __restrict__ T, const float* __restrict__ S,
                 float* __restrict__ X){
    size_t idx = (size_t)blockIdx.x * 256 + threadIdx.x;
    X[idx] = (T[idx] + S[idx] + X[idx]) * (1.f / 3.f);
}

extern "C" void kernel_launch(void* const* d_in, const int* in_sizes, int n_in,
                              void* d_out, int out_size, void* d_ws, size_t ws_size,
                              hipStream_t stream)
{
    const float* x_enc   = (const float*)d_in[0];
    const float* down_W  = (const float*)d_in[1];
    const float* down_b  = (const float*)d_in[2];
    const float* conv_W  = (const float*)d_in[3];
    const float* conv_b  = (const float*)d_in[4];
    const float* up_W    = (const float*)d_in[5];
    const float* up_b    = (const float*)d_in[6];
    const float* bc_g    = (const float*)d_in[7];
    const float* bc_b    = (const float*)d_in[8];
    const float* aWq     = (const float*)d_in[9];
    const float* aWk     = (const float*)d_in[10];
    const float* aWv     = (const float*)d_in[11];
    const float* afcW    = (const float*)d_in[12];
    const float* afcb    = (const float*)d_in[13];
    const float* alng    = (const float*)d_in[14];
    const float* alnb    = (const float*)d_in[15];
    const float* fW1     = (const float*)d_in[16];
    const float* fb1     = (const float*)d_in[17];
    const float* fW2     = (const float*)d_in[18];
    const float* fb2     = (const float*)d_in[19];
    const float* flng    = (const float*)d_in[20];
    const float* flnb    = (const float*)d_in[21];

    const size_t NBL = (size_t)BB * LT * 512;   // 2,785,280
    float* X   = (float*)d_ws;
    float* TMP = X   + NBL;
    float* Qb  = TMP + NBL;
    float* Kb  = Qb  + NBL;
    float* Vb  = Kb  + NBL;
    float* AO  = Vb  + NBL;
    float* TO  = AO  + NBL;
    float* SO  = TO  + NBL;
    uint8_t* SM = (uint8_t*)(SO + NBL);          // B*LT*LT bytes (semantic banned mask)
    int* TIDX = (int*)(SM + (size_t)BB * LT * LT);
    int* TCNT = TIDX + (size_t)LT * 12;
    size_t need = 8 * NBL * sizeof(float) + (size_t)BB * LT * LT + (size_t)LT * 13 * 4;
    if (ws_size < need) return;

    // aliases (lifetimes disjoint)
    float* Y    = Qb;                 // down output (B,1024,512)
    float* C1   = Kb;                 // (B,256,512)
    float* C2   = C1 + (size_t)BB*256*512;
    float* C3   = C2 + (size_t)BB*64*512;
    float* PCAT = Vb;                 // (B,336,512)
    float* WR0  = TO;                 // 3 x (2048,512) repacked conv weights (spills into SO, unused then)
    float* WR1  = WR0 + (size_t)2048*512;
    float* WR2  = WR1 + (size_t)2048*512;
    float* XN   = AO;                 // normalized rows for semantic sim
    float* Hf   = Qb;                 // FFN hidden

    auto gemm = [&](const float* A, const float* Bm, const float* bias,
                    const float* res, float* C, int M, int N, int K,
                    int mpb, int orpb, int ooff, int act){
        dim3 grid(N / 64, M / 64);
        gemm_f32<<<grid, 256, 0, stream>>>(A, Bm, bias, res, C, M, N, K, mpb, orpb, ooff, act);
    };

    build_tidx<<<(LT + 255) / 256, 256, 0, stream>>>(TIDX, TCNT);
    repack_w<<<4096, 256, 0, stream>>>(conv_W + 0 * (size_t)512*512*4, WR0);
    repack_w<<<4096, 256, 0, stream>>>(conv_W + 1 * (size_t)512*512*4, WR1);
    repack_w<<<4096, 256, 0, stream>>>(conv_W + 2 * (size_t)512*512*4, WR2);

    // ---- bottleneck
    gemm(x_enc, down_W, down_b, nullptr, Y, BB*1024, 512, 512, BB*1024, 0, 0, 0);
    gemm(Y,  WR0, conv_b + 0,    nullptr, C1, BB*256, 512, 2048, BB*256, 0, 0, 1);
    gemm(C1, WR1, conv_b + 512,  nullptr, C2, BB*64,  512, 2048, BB*64,  0, 0, 1);
    gemm(C2, WR2, conv_b + 1024, nullptr, C3, BB*16,  512, 2048, BB*16,  0, 0, 1);
    pcat_copy<<<(BB*336*512)/256, 256, 0, stream>>>(C1, C2, C3, PCAT);
    gemm(PCAT, up_W, up_b, nullptr, TMP, BB*336, 512, 512, 336, LT, 1024, 0);
    xenc_copy<<<(BB*1024*512)/256, 256, 0, stream>>>(x_enc, TMP);
    ln_kernel<<<(BB*LT)/4, 256, 0, stream>>>(TMP, bc_g, bc_b, X, 1e-5f);

    // ---- transformer layers
    for (int l = 0; l < 2; l++){
        hipMemsetAsync(SM, 0, (size_t)BB * LT * LT, stream);
        rownorm_kernel<<<(BB*LT)/4, 256, 0, stream>>>(X, XN);
        topk_kernel<<<BB*LT, 256, 0, stream>>>(XN, SM);

        for (int j = 0; j < 2; j++){
            const float* Wq = aWq  + ((size_t)(l*2 + j)) * 512 * 512;
            const float* Wk = aWk  + ((size_t)(l*2 + j)) * 512 * 512;
            const float* Wv = aWv  + ((size_t)(l*2 + j)) * 512 * 512;
            const float* Wf = afcW + ((size_t)(l*2 + j)) * 512 * 512;
            const float* bf = afcb + (size_t)(l*2 + j) * 512;
            const float* lg = alng + (size_t)(l*2 + j) * 512;
            const float* lb = alnb + (size_t)(l*2 + j) * 512;
            gemm(X, Wq, nullptr, nullptr, Qb, BB*LT, 512, 512, BB*LT, 0, 0, 0);
            gemm(X, Wk, nullptr, nullptr, Kb, BB*LT, 512, 512, BB*LT, 0, 0, 0);
            gemm(X, Wv, nullptr, nullptr, Vb, BB*LT, 512, 512, BB*LT, 0, 0, 0);
            if (j == 0)
                attn_sparse<<<(BB*NHH*LT)/4, 256, 0, stream>>>(Qb, Kb, Vb, TIDX, TCNT, AO);
            else
                flash_attn<<<dim3(22, 32), 256, 0, stream>>>(Qb, Kb, Vb, SM, (long)LT*LT, AO);
            gemm(AO, Wf, bf, X, TMP, BB*LT, 512, 512, BB*LT, 0, 0, 0);
            ln_kernel<<<(BB*LT)/4, 256, 0, stream>>>(TMP, lg, lb, (j == 0) ? TO : SO, 1e-6f);
        }
        add3_kernel<<<(int)(NBL/256), 256, 0, stream>>>(TO, SO, X);

        // FFN
        gemm(X,  fW1 + (size_t)l*512*512, fb1 + (size_t)l*512, nullptr, Hf, BB*LT, 512, 512, BB*LT, 0, 0, 2);
        gemm(Hf, fW2 + (size_t)l*512*512, fb2 + (size_t)l*512, X,       TMP, BB*LT, 512, 512, BB*LT, 0, 0, 0);
        ln_kernel<<<(BB*LT)/4, 256, 0, stream>>>(TMP, flng + (size_t)l*512, flnb + (size_t)l*512,
                                                 (l == 1) ? (float*)d_out : X, 1e-6f);
    }
}